// Round 17
// baseline (72.780 us; speedup 1.0000x reference)
//
#include <hip/hip_runtime.h>
#include <hip/hip_bf16.h>

// Problem: B=4, S=128, H=768, OUT*TAG=96
// scores[b,i,j,o] = sum_k relu(head[b,i,k] + tail[b,j,k] + b1[k]) * W2[k,o] + b2[o]
// R16: k_pair = in-block K-split. 512-thr blocks (8 waves), tile 8i x 32j, grid 256
//      (1 block/CU, 2 waves/SIMD). Wave-group g = w>>2 does K-chunks [18g,18g+18)
//      with its own LDS dbuf pair; epilogue LDS-reduction combines partials.
//      Stage-after-barrier depth-1, counted vmcnt(8), setprio MFMA cluster.

typedef __bf16 bf16x8 __attribute__((ext_vector_type(8)));
typedef _Float16 f16x8 __attribute__((ext_vector_type(8)));
typedef float f32x4 __attribute__((ext_vector_type(4)));

#define S_   128
#define H_   768
#define K3   2304   // 3*H
#define NOUT 96
#define NITG 18     // K-step-64 iterations per wave-group (36 total / 2 groups)

__device__ __forceinline__ unsigned short f2bf(float f) {
    union { __bf16 b; unsigned short u; } c;
    c.b = (__bf16)f;   // RNE
    return c.u;
}

__device__ __forceinline__ unsigned short f2h(float f) {
    union { _Float16 h; unsigned short u; } c;
    c.h = (_Float16)f;
    return c.u;
}

__device__ __forceinline__ void gload_lds16(const unsigned short* g, unsigned short* l) {
    __builtin_amdgcn_global_load_lds(
        (const __attribute__((address_space(1))) void*)g,
        (__attribute__((address_space(3))) void*)l,
        16, 0, 0);
}

// ---------- fused prep: cvt_x | transpose W1 | pack W2 (role by blockIdx.x) ----------
__global__ __launch_bounds__(256) void k_prep(
        const float* __restrict__ x, unsigned short* __restrict__ xb,
        const float* __restrict__ W1, unsigned short* __restrict__ w1t,
        const float* __restrict__ W2, unsigned short* __restrict__ w2f) {
    __shared__ float tile[32][33];
    const int bid = blockIdx.x, tid = threadIdx.x;
    if (bid < 384) {
        int t = bid * 256 + tid;
        float4 v = ((const float4*)x)[t];
        ushort4 o;
        o.x = f2bf(v.x); o.y = f2bf(v.y); o.z = f2bf(v.z); o.w = f2bf(v.w);
        ((ushort4*)xb)[t] = o;
    } else if (bid < 3840) {
        int idx = bid - 384;
        int bx = idx % 72, by = (idx / 72) % 24, bz = idx / 1728;   // 72 x 24 x 2
        const float* src = W1 + (size_t)bz * H_ * K3;
        unsigned short* dst = w1t + (size_t)bz * K3 * H_;
        int c0 = bx * 32, r0 = by * 32;
        int row = tid >> 3, c4 = (tid & 7) * 4;
        float4 v = *(const float4*)(src + (size_t)(r0 + row) * K3 + c0 + c4);
        tile[row][c4 + 0] = v.x; tile[row][c4 + 1] = v.y;
        tile[row][c4 + 2] = v.z; tile[row][c4 + 3] = v.w;
        __syncthreads();
        ushort4 o;
        o.x = f2bf(tile[c4 + 0][row]); o.y = f2bf(tile[c4 + 1][row]);
        o.z = f2bf(tile[c4 + 2][row]); o.w = f2bf(tile[c4 + 3][row]);
        *(ushort4*)(dst + (size_t)(c0 + row) * H_ + r0 + c4) = o;
    } else {
        int t = (bid - 3840) * 256 + tid;   // 27648 exact
        int l = t & 63, f = (t >> 6) % 6, kc = t / 384;
        int k0 = kc * 32 + (l >> 4) * 8;
        int o  = f * 16 + (l & 15);
        unsigned short v[8];
#pragma unroll
        for (int e = 0; e < 8; e++)
            v[e] = f2h(W2[(size_t)(k0 + e) * NOUT + o]);
        *(uint4*)(w2f + (size_t)t * 8) = *(const uint4*)v;
    }
}

// ---------- GEMM1: 64x128 tiles (288 blocks), bf16 MFMA, f16 outputs ----------
__global__ __launch_bounds__(256) void k_gemm1(
        const unsigned short* __restrict__ xb,     // [512][768] bf16
        const unsigned short* __restrict__ w1t,    // [4608][768] bf16
        const float* __restrict__ b1,              // [2304]
        unsigned short* __restrict__ headh,        // [512][2304] f16
        unsigned short* __restrict__ tailh) {      // [512][2304] f16
    __shared__ unsigned short As[64 * 32];
    __shared__ unsigned short Bs[128 * 32];
    const int tid = threadIdx.x;
    const int l = tid & 63, w = tid >> 6;
    const int m0 = blockIdx.y * 64;
    const int n0 = blockIdx.x * 128;
    const int wr = (w >> 1) * 32, wc = (w & 1) * 64;
    const int lr = l & 15, lk = (l >> 4) * 8;
    f32x4 acc[2][4] = {};

    for (int kt = 0; kt < H_; kt += 32) {
        {
            int row = tid >> 2, seg = (tid & 3) * 8;
            gload_lds16(xb + (size_t)(m0 + row) * H_ + kt + seg, As + tid * 8);
        }
#pragma unroll
        for (int p = 0; p < 2; ++p) {
            int idx = p * 256 + tid;
            int row = idx >> 2, seg = (idx & 3) * 8;
            gload_lds16(w1t + (size_t)(n0 + row) * H_ + kt + seg, Bs + idx * 8);
        }
        asm volatile("s_waitcnt vmcnt(0)" ::: "memory");
        __syncthreads();
        bf16x8 af[2], bfr[4];
#pragma unroll
        for (int i = 0; i < 2; i++) af[i]  = *(const bf16x8*)(As + (wr + i * 16 + lr) * 32 + lk);
#pragma unroll
        for (int j = 0; j < 4; j++) bfr[j] = *(const bf16x8*)(Bs + (wc + j * 16 + lr) * 32 + lk);
#pragma unroll
        for (int i = 0; i < 2; i++)
#pragma unroll
            for (int j = 0; j < 4; j++)
                acc[i][j] = __builtin_amdgcn_mfma_f32_16x16x32_bf16(af[i], bfr[j], acc[i][j], 0, 0, 0);
        __syncthreads();
    }

    const bool tailblk = (n0 >= K3);
    unsigned short* dst = tailblk ? tailh : headh;
    const int nloc = n0 - (tailblk ? K3 : 0);
    const int lv = (l >> 4) * 4;
#pragma unroll
    for (int j = 0; j < 4; j++) {
        int c = nloc + wc + j * 16 + lr;
        float bias = tailblk ? b1[c] : 0.0f;
#pragma unroll
        for (int i = 0; i < 2; i++) {
            int mrow = m0 + wr + i * 16 + lv;
#pragma unroll
            for (int e = 0; e < 4; e++)
                dst[(size_t)(mrow + e) * K3 + c] = f2h(acc[i][j][e] + bias);
        }
    }
}

// ---------- main pair kernel: in-block K-split ----------
// 512 thr = 8 waves. Wave w: group g=w>>2 (K-chunks [18g,18g+18)), i-slot wi=w&3.
// Tile 8i x 32j; wave computes 2i x 32j partial for its K half.
// LDS: 4 x 12KB = dbuf pair per group. Stage-after-barrier depth-1, vmcnt(8).
// Epilogue: group 1 -> LDS -> group 0 adds, then writes.
__device__ __forceinline__ f16x8 form8h(uint4 hq, uint4 tq) {
    union { uint4 q; f16x8 v; } H, T;
    H.q = hq; T.q = tq;
    f16x8 s = H.v + T.v;
    const f16x8 z = {0, 0, 0, 0, 0, 0, 0, 0};
    return __builtin_elementwise_max(s, z);
}

__global__ __launch_bounds__(512) void k_pair(
        const unsigned short* __restrict__ headh,  // [512][2304] f16
        const unsigned short* __restrict__ tailh,  // [512][2304] f16
        const unsigned short* __restrict__ w2f,    // [72][6][64][8] f16 frag order
        const float* __restrict__ b2,              // [96]
        float* __restrict__ out) {                 // [4][128][128][96] fp32
    __shared__ __align__(16) unsigned short lds[4][6144];   // 48KB: {buf0,buf1} x {g0,g1}

    const int tid = threadIdx.x;
    const int w = tid >> 6, l = tid & 63;
    const int g  = w >> 2;          // K-group 0/1
    const int wi = w & 3;           // i-slot
    const int tg = tid & 255;       // thread index within group
    const int lr = l & 15, lkq = l >> 4;
    const int lkoff = lkq * 8;
    const int ig = blockIdx.x;      // 0..15 (8-i groups)
    const int jb = blockIdx.y;      // 0..3  (32-j groups)
    const int b  = blockIdx.z;      // 0..3
    const int i0 = ig * 8 + wi * 2;
    const int cbase = g * NITG;

    const unsigned short* Hp = headh + (size_t)(b * S_ + i0) * K3;
    const unsigned short* T0 = tailh + (size_t)(b * S_ + jb * 32 + lr) * K3;
    const unsigned short* T1 = T0 + (size_t)16 * K3;

    f32x4 acc[2][2][6] = {};   // [qi][jg][f]

    // stage chunk c (12KB) into lds[sbuf]: 3 x 16B per thread (256 thr per group)
    auto stage = [&](int sbuf, int c) {
        const unsigned short* src = w2f + (size_t)c * 6144;
#pragma unroll
        for (int i = 0; i < 3; ++i)
            gload_lds16(src + i * 2048 + tg * 8, &lds[sbuf][i * 2048 + tg * 8]);
    };

    stage(g * 2, cbase);
    // ht(0): 8 loads
    uint4 tc[2][2], hc[2][2];   // tc[jg][kk], hc[qi][kk]
#pragma unroll
    for (int kk = 0; kk < 2; kk++) {
        const int kb = cbase * 64 + kk * 32 + lkoff;
        tc[0][kk] = *(const uint4*)(T0 + kb);
        tc[1][kk] = *(const uint4*)(T1 + kb);
        hc[0][kk] = *(const uint4*)(Hp + kb);
        hc[1][kk] = *(const uint4*)(Hp + K3 + kb);
    }
    asm volatile("s_waitcnt vmcnt(0)" ::: "memory");
    __builtin_amdgcn_s_barrier();

    for (int n = 0; n < NITG; ++n) {
        // ht(n+1) prefetch [8 loads; clamped on last iter]
        const int cn = cbase + ((n < NITG - 1) ? n + 1 : n);
        uint4 tn[2][2], hn[2][2];
#pragma unroll
        for (int kk = 0; kk < 2; kk++) {
            const int kb = cn * 64 + kk * 32 + lkoff;
            tn[0][kk] = *(const uint4*)(T0 + kb);
            tn[1][kk] = *(const uint4*)(T1 + kb);
            hn[0][kk] = *(const uint4*)(Hp + kb);
            hn[1][kk] = *(const uint4*)(Hp + K3 + kb);
        }

        // outstanding (oldest->newest): stage(n)[3] + ht(n+1)[8].
        // vmcnt(8) retires stage(n) (buf about to be read), keeps ht(n+1) in flight.
        asm volatile("s_waitcnt vmcnt(8)" ::: "memory");
        __builtin_amdgcn_s_barrier();

        // stage(n+1) after barrier (WAR-safe: buf (n+1)&1's readers were compute(n-1),
        // whose ds_reads finished before they reached barrier(n)). Clamped dummy last iter.
        stage(g * 2 + ((n + 1) & 1), cbase + ((n + 1 < NITG) ? n + 1 : n));

        const unsigned short* Lb = &lds[g * 2 + (n & 1)][0];
        __builtin_amdgcn_s_setprio(1);
#pragma unroll
        for (int kk = 0; kk < 2; kk++) {
            f16x8 a[2][2];
#pragma unroll
            for (int qi = 0; qi < 2; qi++)
#pragma unroll
                for (int jg = 0; jg < 2; jg++)
                    a[qi][jg] = form8h(hc[qi][kk], tc[jg][kk]);
#pragma unroll
            for (int f = 0; f < 6; f++) {
                f16x8 bfr = *(const f16x8*)(Lb + kk * 3072 + f * 512 + l * 8);
#pragma unroll
                for (int qi = 0; qi < 2; qi++)
#pragma unroll
                    for (int jg = 0; jg < 2; jg++)
                        acc[qi][jg][f] = __builtin_amdgcn_mfma_f32_16x16x32_f16(
                            a[qi][jg], bfr, acc[qi][jg][f], 0, 0, 0);
            }
        }
        __builtin_amdgcn_s_setprio(0);
#pragma unroll
        for (int kk = 0; kk < 2; kk++) {
            tc[0][kk] = tn[0][kk]; tc[1][kk] = tn[1][kk];
            hc[0][kk] = hn[0][kk]; hc[1][kk] = hn[1][kk];
        }
    }

    // drain the dummy stage DMA before reusing LDS for the reduction
    asm volatile("s_waitcnt vmcnt(0)" ::: "memory");
    __syncthreads();

    // K-split reduction: group 1 dumps accs to LDS, group 0 adds. 3 rounds x 8 f32x4.
    float4* red = (float4*)&lds[0][0];           // [4 waves][64 lanes][8 slots] = 32KB
    const int rbase = (wi * 64 + l) * 8;
#pragma unroll
    for (int r = 0; r < 3; r++) {
        if (g == 1) {
#pragma unroll
            for (int s = 0; s < 8; s++) {
                const int idx = r * 8 + s;               // compile-time constant
                const int qi = idx / 12, jg = (idx % 12) / 6, f = idx % 6;
                f32x4 v = acc[qi][jg][f];
                red[rbase + s] = make_float4(v[0], v[1], v[2], v[3]);
            }
        }
        __syncthreads();
        if (g == 0) {
#pragma unroll
            for (int s = 0; s < 8; s++) {
                const int idx = r * 8 + s;
                const int qi = idx / 12, jg = (idx % 12) / 6, f = idx % 6;
                float4 v = red[rbase + s];
                acc[qi][jg][f][0] += v.x; acc[qi][jg][f][1] += v.y;
                acc[qi][jg][f][2] += v.z; acc[qi][jg][f][3] += v.w;
            }
        }
        __syncthreads();
    }

    if (g == 0) {
        float b2v[6];
#pragma unroll
        for (int f = 0; f < 6; f++) b2v[f] = b2[f * 16 + lr];
#pragma unroll
        for (int qi = 0; qi < 2; qi++) {
            float* O = out + ((size_t)(b * S_ + i0 + qi) * S_ + jb * 32) * NOUT;
#pragma unroll
            for (int jg = 0; jg < 2; jg++)
#pragma unroll
                for (int f = 0; f < 6; f++)
#pragma unroll
                    for (int e = 0; e < 4; e++) {
                        int j = jg * 16 + lkq * 4 + e;
                        O[(size_t)j * NOUT + f * 16 + lr] = acc[qi][jg][f][e] + b2v[f];
                    }
        }
    }
}

extern "C" void kernel_launch(void* const* d_in, const int* in_sizes, int n_in,
                              void* d_out, int out_size, void* d_ws, size_t ws_size,
                              hipStream_t stream) {
    const float* x  = (const float*)d_in[0];   // [4][128][768]
    const float* W1 = (const float*)d_in[1];   // [1536][2304]
    const float* b1 = (const float*)d_in[2];   // [2304]
    const float* W2 = (const float*)d_in[3];   // [2304][96]
    const float* b2 = (const float*)d_in[4];   // [96]
    float* out = (float*)d_out;

    char* ws = (char*)d_ws;
    unsigned short* xb    = (unsigned short*)(ws);              //  512*768   bf16
    unsigned short* w1t   = (unsigned short*)(ws +   786432);   // 4608*768   bf16
    unsigned short* w2f   = (unsigned short*)(ws +  7864320);   //  72*6*64*8 f16
    unsigned short* headh = (unsigned short*)(ws +  8306688);   //  512*2304  f16
    unsigned short* tailh = (unsigned short*)(ws + 10665984);   //  512*2304  f16
    // total ws use: 13,025,280 bytes

    hipLaunchKernelGGL(k_prep, dim3(3948), dim3(256), 0, stream,
                       x, xb, W1, w1t, W2, w2f);
    hipLaunchKernelGGL(k_gemm1, dim3(36, 8), dim3(256), 0, stream,
                       xb, w1t, b1, headh, tailh);
    hipLaunchKernelGGL(k_pair, dim3(16, 4, 4), dim3(512), 0, stream,
                       headh, tailh, w2f, b2, out);
}

// Round 18
// 69.410 us; speedup vs baseline: 1.0486x; 1.0486x over previous
//
#include <hip/hip_runtime.h>
#include <hip/hip_bf16.h>

// Problem: B=4, S=128, H=768, OUT*TAG=96
// scores[b,i,j,o] = sum_k relu(head[b,i,k] + tail[b,j,k] + b1[k]) * W2[k,o] + b2[o]
// R17: k_pair = barrier-free pure-register main loop on mfma_32x32x16_f16.
//      Wave = 2i x 32j, in-block K-split (4 waves = 2 khalf x 2 i-slot),
//      512 blocks -> 8 waves/CU (2/SIMD). W2 streamed L2->reg (6 b128/iter,
//      depth-1, vmcnt(12)-fenced). LDS only for the K-split reduction (24KB).

typedef __bf16 bf16x8 __attribute__((ext_vector_type(8)));
typedef _Float16 f16x8 __attribute__((ext_vector_type(8)));
typedef float f32x4 __attribute__((ext_vector_type(4)));
typedef float f32x16 __attribute__((ext_vector_type(16)));

#define S_   128
#define H_   768
#define K3   2304   // 3*H
#define NOUT 96
#define NITG 36     // K-step-32 iterations per wave (half of 72)

__device__ __forceinline__ unsigned short f2bf(float f) {
    union { __bf16 b; unsigned short u; } c;
    c.b = (__bf16)f;   // RNE
    return c.u;
}

__device__ __forceinline__ unsigned short f2h(float f) {
    union { _Float16 h; unsigned short u; } c;
    c.h = (_Float16)f;
    return c.u;
}

__device__ __forceinline__ void gload_lds16(const unsigned short* g, unsigned short* l) {
    __builtin_amdgcn_global_load_lds(
        (const __attribute__((address_space(1))) void*)g,
        (__attribute__((address_space(3))) void*)l,
        16, 0, 0);
}

// ---------- fused prep: cvt_x | transpose W1 | pack W2 (role by blockIdx.x) ----------
// pack W2 in 32x32-frag order [144 slices][3 og][64 lanes][8]:
//   elem(s,og,l,e) = W2[s*16 + (l>>5)*8 + e][og*32 + (l&31)]   (R11-verified layout)
__global__ __launch_bounds__(256) void k_prep(
        const float* __restrict__ x, unsigned short* __restrict__ xb,
        const float* __restrict__ W1, unsigned short* __restrict__ w1t,
        const float* __restrict__ W2, unsigned short* __restrict__ w2f) {
    __shared__ float tile[32][33];
    const int bid = blockIdx.x, tid = threadIdx.x;
    if (bid < 384) {
        int t = bid * 256 + tid;
        float4 v = ((const float4*)x)[t];
        ushort4 o;
        o.x = f2bf(v.x); o.y = f2bf(v.y); o.z = f2bf(v.z); o.w = f2bf(v.w);
        ((ushort4*)xb)[t] = o;
    } else if (bid < 3840) {
        int idx = bid - 384;
        int bx = idx % 72, by = (idx / 72) % 24, bz = idx / 1728;   // 72 x 24 x 2
        const float* src = W1 + (size_t)bz * H_ * K3;
        unsigned short* dst = w1t + (size_t)bz * K3 * H_;
        int c0 = bx * 32, r0 = by * 32;
        int row = tid >> 3, c4 = (tid & 7) * 4;
        float4 v = *(const float4*)(src + (size_t)(r0 + row) * K3 + c0 + c4);
        tile[row][c4 + 0] = v.x; tile[row][c4 + 1] = v.y;
        tile[row][c4 + 2] = v.z; tile[row][c4 + 3] = v.w;
        __syncthreads();
        ushort4 o;
        o.x = f2bf(tile[c4 + 0][row]); o.y = f2bf(tile[c4 + 1][row]);
        o.z = f2bf(tile[c4 + 2][row]); o.w = f2bf(tile[c4 + 3][row]);
        *(ushort4*)(dst + (size_t)(c0 + row) * H_ + r0 + c4) = o;
    } else {
        int t = (bid - 3840) * 256 + tid;   // 27648 exact = 144*3*64
        int l = t & 63, og = (t >> 6) % 3, s = t / 192;
        int k0 = s * 16 + (l >> 5) * 8;
        int o  = og * 32 + (l & 31);
        unsigned short v[8];
#pragma unroll
        for (int e = 0; e < 8; e++)
            v[e] = f2h(W2[(size_t)(k0 + e) * NOUT + o]);
        *(uint4*)(w2f + (size_t)t * 8) = *(const uint4*)v;
    }
}

// ---------- GEMM1: 64x128 tiles (288 blocks), bf16 MFMA, f16 outputs ----------
__global__ __launch_bounds__(256) void k_gemm1(
        const unsigned short* __restrict__ xb,     // [512][768] bf16
        const unsigned short* __restrict__ w1t,    // [4608][768] bf16
        const float* __restrict__ b1,              // [2304]
        unsigned short* __restrict__ headh,        // [512][2304] f16
        unsigned short* __restrict__ tailh) {      // [512][2304] f16
    __shared__ unsigned short As[64 * 32];
    __shared__ unsigned short Bs[128 * 32];
    const int tid = threadIdx.x;
    const int l = tid & 63, w = tid >> 6;
    const int m0 = blockIdx.y * 64;
    const int n0 = blockIdx.x * 128;
    const int wr = (w >> 1) * 32, wc = (w & 1) * 64;
    const int lr = l & 15, lk = (l >> 4) * 8;
    f32x4 acc[2][4] = {};

    for (int kt = 0; kt < H_; kt += 32) {
        {
            int row = tid >> 2, seg = (tid & 3) * 8;
            gload_lds16(xb + (size_t)(m0 + row) * H_ + kt + seg, As + tid * 8);
        }
#pragma unroll
        for (int p = 0; p < 2; ++p) {
            int idx = p * 256 + tid;
            int row = idx >> 2, seg = (idx & 3) * 8;
            gload_lds16(w1t + (size_t)(n0 + row) * H_ + kt + seg, Bs + idx * 8);
        }
        asm volatile("s_waitcnt vmcnt(0)" ::: "memory");
        __syncthreads();
        bf16x8 af[2], bfr[4];
#pragma unroll
        for (int i = 0; i < 2; i++) af[i]  = *(const bf16x8*)(As + (wr + i * 16 + lr) * 32 + lk);
#pragma unroll
        for (int j = 0; j < 4; j++) bfr[j] = *(const bf16x8*)(Bs + (wc + j * 16 + lr) * 32 + lk);
#pragma unroll
        for (int i = 0; i < 2; i++)
#pragma unroll
            for (int j = 0; j < 4; j++)
                acc[i][j] = __builtin_amdgcn_mfma_f32_16x16x32_bf16(af[i], bfr[j], acc[i][j], 0, 0, 0);
        __syncthreads();
    }

    const bool tailblk = (n0 >= K3);
    unsigned short* dst = tailblk ? tailh : headh;
    const int nloc = n0 - (tailblk ? K3 : 0);
    const int lv = (l >> 4) * 4;
#pragma unroll
    for (int j = 0; j < 4; j++) {
        int c = nloc + wc + j * 16 + lr;
        float bias = tailblk ? b1[c] : 0.0f;
#pragma unroll
        for (int i = 0; i < 2; i++) {
            int mrow = m0 + wr + i * 16 + lv;
#pragma unroll
            for (int e = 0; e < 4; e++)
                dst[(size_t)(mrow + e) * K3 + c] = f2h(acc[i][j][e] + bias);
        }
    }
}

// ---------- main pair kernel: barrier-free, pure-register, 32x32x16 f16 ----------
// 256 thr = 4 waves: wave w -> (g = w>>1 : K-half, wi = w&1 : i-slot).
// Wave computes 2i x 32j over k in [g*1152, (g+1)*1152), K-step 32.
// Per iter: [6 W2 b128 loads (n+1)][6 ht loads (n+1)][vmcnt(12)][4 forms, 12 MFMA].
// No LDS / no barriers in the loop; epilogue K-split reduction via 24KB LDS.
__device__ __forceinline__ f16x8 form8h(uint4 hq, uint4 tq) {
    union { uint4 q; f16x8 v; } H, T;
    H.q = hq; T.q = tq;
    f16x8 s = H.v + T.v;
    const f16x8 z = {0, 0, 0, 0, 0, 0, 0, 0};
    return __builtin_elementwise_max(s, z);
}

__device__ __forceinline__ f16x8 u4f16(uint4 v) {
    union { uint4 q; f16x8 b; } c; c.q = v; return c.b;
}

__global__ __launch_bounds__(256, 2) void k_pair(
        const unsigned short* __restrict__ headh,  // [512][2304] f16
        const unsigned short* __restrict__ tailh,  // [512][2304] f16
        const unsigned short* __restrict__ w2f,    // [144][3][64][8] f16 frag order
        const float* __restrict__ b2,              // [96]
        float* __restrict__ out) {                 // [4][128][128][96] fp32
    __shared__ __align__(16) float4 red[2][3][64][4];   // 24KB, reduction only

    const int tid = threadIdx.x;
    const int w = tid >> 6, l = tid & 63;
    const int g  = w >> 1;          // K-half
    const int wi = w & 1;           // i-slot
    const int lo = l & 31;          // j (and o) sub-index
    const int ko = (l >> 5) * 8;    // k half-slice offset
    const int jb = blockIdx.x;      // 0..3   (32-j groups)
    const int ig = blockIdx.y;      // 0..31  (4-i groups)
    const int b  = blockIdx.z;      // 0..3
    const int i0 = ig * 4 + wi * 2;
    const int cbase = g * NITG;     // K-32 chunk base

    const unsigned short* Hp = headh + (size_t)(b * S_ + i0) * K3;
    const unsigned short* Tp = tailh + (size_t)(b * S_ + jb * 32 + lo) * K3;
    const unsigned short* Wp = w2f + l * 8;

    f32x16 acc[2][3] = {};   // [qi][og]

    // prologue: W2(0) + ht(0)
    uint4 wcur[6], wnxt[6];
#pragma unroll
    for (int si = 0; si < 2; si++)
#pragma unroll
        for (int og = 0; og < 3; og++)
            wcur[si * 3 + og] = *(const uint4*)(Wp + ((size_t)(2 * cbase + si) * 3 + og) * 512);
    uint4 tc[2], hc[2][2], tn[2], hn[2][2];
#pragma unroll
    for (int si = 0; si < 2; si++) {
        const int kb = cbase * 32 + si * 16 + ko;
        tc[si]    = *(const uint4*)(Tp + kb);
        hc[0][si] = *(const uint4*)(Hp + kb);
        hc[1][si] = *(const uint4*)(Hp + K3 + kb);
    }

    for (int n = 0; n < NITG; ++n) {
        const int cn = cbase + ((n < NITG - 1) ? n + 1 : n);   // clamped
        // W2(n+1) prefetch [6]
#pragma unroll
        for (int si = 0; si < 2; si++)
#pragma unroll
            for (int og = 0; og < 3; og++)
                wnxt[si * 3 + og] = *(const uint4*)(Wp + ((size_t)(2 * cn + si) * 3 + og) * 512);
        // ht(n+1) prefetch [6]
#pragma unroll
        for (int si = 0; si < 2; si++) {
            const int kb = cn * 32 + si * 16 + ko;
            tn[si]    = *(const uint4*)(Tp + kb);
            hn[0][si] = *(const uint4*)(Hp + kb);
            hn[1][si] = *(const uint4*)(Hp + K3 + kb);
        }
        // keep the 12 just-issued loads in flight; everything older (cur data) done.
        // memory clobber also pins the prefetches above this point (no sinking).
        asm volatile("s_waitcnt vmcnt(12)" ::: "memory");

        __builtin_amdgcn_s_setprio(1);
#pragma unroll
        for (int si = 0; si < 2; si++) {
            f16x8 a0 = form8h(hc[0][si], tc[si]);
            f16x8 a1 = form8h(hc[1][si], tc[si]);
#pragma unroll
            for (int og = 0; og < 3; og++) {
                f16x8 bfr = u4f16(wcur[si * 3 + og]);
                acc[0][og] = __builtin_amdgcn_mfma_f32_32x32x16_f16(a0, bfr, acc[0][og], 0, 0, 0);
                acc[1][og] = __builtin_amdgcn_mfma_f32_32x32x16_f16(a1, bfr, acc[1][og], 0, 0, 0);
            }
        }
        __builtin_amdgcn_s_setprio(0);

#pragma unroll
        for (int s = 0; s < 6; s++) wcur[s] = wnxt[s];
#pragma unroll
        for (int si = 0; si < 2; si++) {
            tc[si] = tn[si]; hc[0][si] = hn[0][si]; hc[1][si] = hn[1][si];
        }
    }

    // ---- K-split reduction: g1 -> LDS -> g0 adds. 2 rounds (qi = round). ----
    asm volatile("s_waitcnt vmcnt(0) lgkmcnt(0)" ::: "memory");
    __syncthreads();
#pragma unroll
    for (int r = 0; r < 2; r++) {
        if (g == 1) {
#pragma unroll
            for (int s = 0; s < 3; s++)
#pragma unroll
                for (int p = 0; p < 4; p++)
                    red[wi][s][l][p] = make_float4(acc[r][s][p * 4 + 0], acc[r][s][p * 4 + 1],
                                                   acc[r][s][p * 4 + 2], acc[r][s][p * 4 + 3]);
        }
        __syncthreads();
        if (g == 0) {
#pragma unroll
            for (int s = 0; s < 3; s++)
#pragma unroll
                for (int p = 0; p < 4; p++) {
                    float4 v = red[wi][s][l][p];
                    acc[r][s][p * 4 + 0] += v.x; acc[r][s][p * 4 + 1] += v.y;
                    acc[r][s][p * 4 + 2] += v.z; acc[r][s][p * 4 + 3] += v.w;
                }
        }
        __syncthreads();
    }

    if (g == 0) {
        float b2v[3];
#pragma unroll
        for (int og = 0; og < 3; og++) b2v[og] = b2[og * 32 + lo];
        // C/D 32x32 layout (R11-verified): col = og*32+lo, row j = (r&3)+8*(r>>2)+4*(l>>5)
#pragma unroll
        for (int qi = 0; qi < 2; qi++) {
            float* O = out + ((size_t)(b * S_ + i0 + qi) * S_ + jb * 32) * NOUT + lo;
#pragma unroll
            for (int og = 0; og < 3; og++)
#pragma unroll
                for (int r = 0; r < 16; r++) {
                    int j = (r & 3) + 8 * (r >> 2) + 4 * (l >> 5);
                    O[(size_t)j * NOUT + og * 32] = acc[qi][og][r] + b2v[og];
                }
        }
    }
}

extern "C" void kernel_launch(void* const* d_in, const int* in_sizes, int n_in,
                              void* d_out, int out_size, void* d_ws, size_t ws_size,
                              hipStream_t stream) {
    const float* x  = (const float*)d_in[0];   // [4][128][768]
    const float* W1 = (const float*)d_in[1];   // [1536][2304]
    const float* b1 = (const float*)d_in[2];   // [2304]
    const float* W2 = (const float*)d_in[3];   // [2304][96]
    const float* b2 = (const float*)d_in[4];   // [96]
    float* out = (float*)d_out;

    char* ws = (char*)d_ws;
    unsigned short* xb    = (unsigned short*)(ws);              //  512*768   bf16
    unsigned short* w1t   = (unsigned short*)(ws +   786432);   // 4608*768   bf16
    unsigned short* w2f   = (unsigned short*)(ws +  7864320);   //  144*3*64*8 f16
    unsigned short* headh = (unsigned short*)(ws +  8306688);   //  512*2304  f16
    unsigned short* tailh = (unsigned short*)(ws + 10665984);   //  512*2304  f16
    // total ws use: 13,025,280 bytes

    hipLaunchKernelGGL(k_prep, dim3(3948), dim3(256), 0, stream,
                       x, xb, W1, w1t, W2, w2f);
    hipLaunchKernelGGL(k_gemm1, dim3(36, 8), dim3(256), 0, stream,
                       xb, w1t, b1, headh, tailh);
    hipLaunchKernelGGL(k_pair, dim3(4, 32, 4), dim3(256), 0, stream,
                       headh, tailh, w2f, b2, out);
}

// Round 19
// 61.289 us; speedup vs baseline: 1.1875x; 1.1325x over previous
//
#include <hip/hip_runtime.h>
#include <hip/hip_bf16.h>

// Problem: B=4, S=128, H=768, OUT*TAG=96
// scores[b,i,j,o] = sum_k relu(head[b,i,k] + tail[b,j,k] + b1[k]) * W2[k,o] + b2[o]
// R18: k_pair = R10 structure (best measured: ring-4 W2 LDS DMA, counted vmcnt,
//      16x16 frags, 4-wave blocks, grid 512) + TAIL STAGED IN LDS: gemm1 writes
//      tail in transposed chunk layout [jbg][chunk][u][row][e]; k_pair stages it
//      linearly alongside W2 and reads A-frags via ds_read — no global gathers.

typedef __bf16 bf16x8 __attribute__((ext_vector_type(8)));
typedef _Float16 f16x8 __attribute__((ext_vector_type(8)));
typedef float f32x4 __attribute__((ext_vector_type(4)));

#define S_   128
#define H_   768
#define K3   2304   // 3*H
#define NOUT 96
#define NIT  36     // K-step-64 iterations

__device__ __forceinline__ unsigned short f2bf(float f) {
    union { __bf16 b; unsigned short u; } c;
    c.b = (__bf16)f;   // RNE
    return c.u;
}

__device__ __forceinline__ unsigned short f2h(float f) {
    union { _Float16 h; unsigned short u; } c;
    c.h = (_Float16)f;
    return c.u;
}

__device__ __forceinline__ void gload_lds16(const unsigned short* g, unsigned short* l) {
    __builtin_amdgcn_global_load_lds(
        (const __attribute__((address_space(1))) void*)g,
        (__attribute__((address_space(3))) void*)l,
        16, 0, 0);
}

// ---------- fused prep: cvt_x | transpose W1 | pack W2 (role by blockIdx.x) ----------
// W2 packed in 16x16-frag order [72][6][64][8] (R10-verified):
//   elem(kc,f,l,e) = W2[kc*32 + (l>>4)*8 + e][f*16 + (l&15)]
__global__ __launch_bounds__(256) void k_prep(
        const float* __restrict__ x, unsigned short* __restrict__ xb,
        const float* __restrict__ W1, unsigned short* __restrict__ w1t,
        const float* __restrict__ W2, unsigned short* __restrict__ w2f) {
    __shared__ float tile[32][33];
    const int bid = blockIdx.x, tid = threadIdx.x;
    if (bid < 384) {
        int t = bid * 256 + tid;
        float4 v = ((const float4*)x)[t];
        ushort4 o;
        o.x = f2bf(v.x); o.y = f2bf(v.y); o.z = f2bf(v.z); o.w = f2bf(v.w);
        ((ushort4*)xb)[t] = o;
    } else if (bid < 3840) {
        int idx = bid - 384;
        int bx = idx % 72, by = (idx / 72) % 24, bz = idx / 1728;   // 72 x 24 x 2
        const float* src = W1 + (size_t)bz * H_ * K3;
        unsigned short* dst = w1t + (size_t)bz * K3 * H_;
        int c0 = bx * 32, r0 = by * 32;
        int row = tid >> 3, c4 = (tid & 7) * 4;
        float4 v = *(const float4*)(src + (size_t)(r0 + row) * K3 + c0 + c4);
        tile[row][c4 + 0] = v.x; tile[row][c4 + 1] = v.y;
        tile[row][c4 + 2] = v.z; tile[row][c4 + 3] = v.w;
        __syncthreads();
        ushort4 o;
        o.x = f2bf(tile[c4 + 0][row]); o.y = f2bf(tile[c4 + 1][row]);
        o.z = f2bf(tile[c4 + 2][row]); o.w = f2bf(tile[c4 + 3][row]);
        *(ushort4*)(dst + (size_t)(c0 + row) * H_ + r0 + c4) = o;
    } else {
        int t = (bid - 3840) * 256 + tid;   // 27648 exact
        int l = t & 63, f = (t >> 6) % 6, kc = t / 384;
        int k0 = kc * 32 + (l >> 4) * 8;
        int o  = f * 16 + (l & 15);
        unsigned short v[8];
#pragma unroll
        for (int e = 0; e < 8; e++)
            v[e] = f2h(W2[(size_t)(k0 + e) * NOUT + o]);
        *(uint4*)(w2f + (size_t)t * 8) = *(const uint4*)v;
    }
}

// ---------- GEMM1: 64x128 tiles (288 blocks), bf16 MFMA ----------
// head -> headh row-major f16; tail+b1 -> tailsw [32 jbg][36 chunk][8 u][16 row][8 e] f16
__global__ __launch_bounds__(256) void k_gemm1(
        const unsigned short* __restrict__ xb,     // [512][768] bf16
        const unsigned short* __restrict__ w1t,    // [4608][768] bf16
        const float* __restrict__ b1,              // [2304]
        unsigned short* __restrict__ headh,        // [512][2304] f16
        unsigned short* __restrict__ tailsw) {     // chunked tail, f16
    __shared__ unsigned short As[64 * 32];
    __shared__ unsigned short Bs[128 * 32];
    const int tid = threadIdx.x;
    const int l = tid & 63, w = tid >> 6;
    const int m0 = blockIdx.y * 64;
    const int n0 = blockIdx.x * 128;
    const int wr = (w >> 1) * 32, wc = (w & 1) * 64;
    const int lr = l & 15, lk = (l >> 4) * 8;
    f32x4 acc[2][4] = {};

    for (int kt = 0; kt < H_; kt += 32) {
        {
            int row = tid >> 2, seg = (tid & 3) * 8;
            gload_lds16(xb + (size_t)(m0 + row) * H_ + kt + seg, As + tid * 8);
        }
#pragma unroll
        for (int p = 0; p < 2; ++p) {
            int idx = p * 256 + tid;
            int row = idx >> 2, seg = (idx & 3) * 8;
            gload_lds16(w1t + (size_t)(n0 + row) * H_ + kt + seg, Bs + idx * 8);
        }
        asm volatile("s_waitcnt vmcnt(0)" ::: "memory");
        __syncthreads();
        bf16x8 af[2], bfr[4];
#pragma unroll
        for (int i = 0; i < 2; i++) af[i]  = *(const bf16x8*)(As + (wr + i * 16 + lr) * 32 + lk);
#pragma unroll
        for (int j = 0; j < 4; j++) bfr[j] = *(const bf16x8*)(Bs + (wc + j * 16 + lr) * 32 + lk);
#pragma unroll
        for (int i = 0; i < 2; i++)
#pragma unroll
            for (int j = 0; j < 4; j++)
                acc[i][j] = __builtin_amdgcn_mfma_f32_16x16x32_bf16(af[i], bfr[j], acc[i][j], 0, 0, 0);
        __syncthreads();
    }

    const bool tailblk = (n0 >= K3);
    const int nloc = n0 - (tailblk ? K3 : 0);
    const int lv = (l >> 4) * 4;
    if (!tailblk) {
#pragma unroll
        for (int j = 0; j < 4; j++) {
            int c = nloc + wc + j * 16 + lr;
#pragma unroll
            for (int i = 0; i < 2; i++) {
                int mrow = m0 + wr + i * 16 + lv;
#pragma unroll
                for (int e = 0; e < 4; e++)
                    headh[(size_t)(mrow + e) * K3 + c] = f2h(acc[i][j][e]);
            }
        }
    } else {
#pragma unroll
        for (int j = 0; j < 4; j++) {
            int c = nloc + wc + j * 16 + lr;
            float bias = b1[c];
            int chunk = c >> 6, kin = c & 63, u = kin >> 3, ee = kin & 7;
#pragma unroll
            for (int i = 0; i < 2; i++) {
                int mrow = m0 + wr + i * 16 + lv;
#pragma unroll
                for (int e = 0; e < 4; e++) {
                    int r = mrow + e;                    // global row 0..511
                    int jbg = r >> 4, rr = r & 15;
                    size_t idx = (((size_t)(jbg * 36 + chunk) * 8 + u) * 16 + rr) * 8 + ee;
                    tailsw[idx] = f2h(acc[i][j][e] + bias);
                }
            }
        }
    }
}

// ---------- main pair kernel (R10 + LDS-staged tail) ----------
// 256 thr (4 waves), tile 8i x 16j; wave w owns i = i0+2w, i0+2w+1.
// Ring-4: W2 12KB + tail 2KB per K-64 chunk, staged depth-2 via global_load_lds
// (5 uniform ops/wave/iter; tail duplicated across waves). Head: 4 broadcast
// register-prefetch loads. vmcnt(9) = stage(n+2)[5] + ht(n+1)[4]. Raw s_barrier.
__device__ __forceinline__ f16x8 form8t(uint4 hq, f16x8 t) {
    union { uint4 q; f16x8 v; } H;
    H.q = hq;
    f16x8 s = H.v + t;
    const f16x8 z = {0, 0, 0, 0, 0, 0, 0, 0};
    return __builtin_elementwise_max(s, z);
}

__global__ __launch_bounds__(256) void k_pair(
        const unsigned short* __restrict__ headh,  // [512][2304] f16
        const unsigned short* __restrict__ tailsw, // [32][36][8][16][8] f16
        const unsigned short* __restrict__ w2f,    // [72][6][64][8] f16 frag order
        const float* __restrict__ b2,              // [96]
        float* __restrict__ out) {                 // [4][128][128][96] fp32
    __shared__ __align__(16) unsigned short wlds[4][6144];   // 48KB W2 ring
    __shared__ __align__(16) unsigned short tlds[4][1024];   // 8KB tail ring

    const int tid = threadIdx.x;
    const int w = tid >> 6, l = tid & 63;
    const int lr = l & 15, lkq = l >> 4;
    const int lkoff = lkq * 8;
    const int jb = blockIdx.x;     // 0..7
    const int ig = blockIdx.y;     // 0..15
    const int b  = blockIdx.z;     // 0..3
    const int i0 = ig * 8;

    const unsigned short* Hp   = headh + (size_t)(b * S_ + i0 + 2 * w) * K3;
    const unsigned short* Tsrc = tailsw + (size_t)(b * 8 + jb) * 36 * 1024;

    f32x4 acc[2][6] = {};
    float b2v[6];
#pragma unroll
    for (int f = 0; f < 6; f++) b2v[f] = b2[f * 16 + lr];

    // stage K-64 chunk c into ring sbuf: W2 3 ops + tail 2 ops (uniform per wave)
    auto stage = [&](int sbuf, int c) {
        const unsigned short* wsrc = w2f + (size_t)c * 6144;
#pragma unroll
        for (int i = 0; i < 3; ++i)
            gload_lds16(wsrc + i * 2048 + tid * 8, &wlds[sbuf][i * 2048 + tid * 8]);
        const unsigned short* tsrc = Tsrc + (size_t)c * 1024;
#pragma unroll
        for (int h = 0; h < 2; ++h)
            gload_lds16(tsrc + h * 512 + l * 8, &tlds[sbuf][h * 512 + l * 8]);
    };

    stage(0, 0);
    stage(1, 1);
    // head(0): 4 broadcast loads
    uint4 ha[2], hb[2];
#pragma unroll
    for (int kk = 0; kk < 2; kk++) {
        ha[kk] = *(const uint4*)(Hp + kk * 32 + lkoff);
        hb[kk] = *(const uint4*)(Hp + K3 + kk * 32 + lkoff);
    }

    for (int n = 0; n < NIT; ++n) {
        // depth-2 staging (dummy clamped re-stage keeps vmcnt uniform; target buf's
        // readers finished 2+ iters ago)
        stage((n + 2) & 3, (n + 2 < NIT) ? (n + 2) : (NIT - 1));
        // head(n+1) register prefetch (4 loads; clamped on last iter)
        const int kn = ((n < NIT - 1) ? (n + 1) : n) * 64;
        uint4 han[2], hbn[2];
#pragma unroll
        for (int kk = 0; kk < 2; kk++) {
            han[kk] = *(const uint4*)(Hp + kn + kk * 32 + lkoff);
            hbn[kk] = *(const uint4*)(Hp + K3 + kn + kk * 32 + lkoff);
        }

        // newest 9 = stage(n+2)[5] + head(n+1)[4]; forces stage(n+1)+head(n) done.
        asm volatile("s_waitcnt vmcnt(9)" ::: "memory");
        __builtin_amdgcn_s_barrier();

        const unsigned short* Lb = &wlds[n & 3][0];
        const unsigned short* Tb = &tlds[n & 3][0];
        __builtin_amdgcn_s_setprio(1);
#pragma unroll
        for (int kk = 0; kk < 2; kk++) {
            // tail A-operand from LDS: lane (lr, lkq) reads u = kk*4+lkq, row lr
            f16x8 t8 = *(const f16x8*)(Tb + (kk * 4 + lkq) * 128 + lr * 8);
            f16x8 a0 = form8t(ha[kk], t8);
            f16x8 a1 = form8t(hb[kk], t8);
#pragma unroll
            for (int f = 0; f < 6; f++) {
                f16x8 bfr = *(const f16x8*)(Lb + kk * 3072 + f * 512 + l * 8);
                acc[0][f] = __builtin_amdgcn_mfma_f32_16x16x32_f16(a0, bfr, acc[0][f], 0, 0, 0);
                acc[1][f] = __builtin_amdgcn_mfma_f32_16x16x32_f16(a1, bfr, acc[1][f], 0, 0, 0);
            }
        }
        __builtin_amdgcn_s_setprio(0);
#pragma unroll
        for (int kk = 0; kk < 2; kk++) { ha[kk] = han[kk]; hb[kk] = hbn[kk]; }
    }

    float* O = out + (((size_t)(b * S_ + i0 + 2 * w)) * S_ + jb * 16) * NOUT;
#pragma unroll
    for (int q = 0; q < 2; q++)
#pragma unroll
        for (int f = 0; f < 6; f++)
#pragma unroll
            for (int e = 0; e < 4; e++) {
                int j = lkq * 4 + e;
                O[(size_t)q * S_ * NOUT + (size_t)j * NOUT + f * 16 + lr] = acc[q][f][e] + b2v[f];
            }
}

extern "C" void kernel_launch(void* const* d_in, const int* in_sizes, int n_in,
                              void* d_out, int out_size, void* d_ws, size_t ws_size,
                              hipStream_t stream) {
    const float* x  = (const float*)d_in[0];   // [4][128][768]
    const float* W1 = (const float*)d_in[1];   // [1536][2304]
    const float* b1 = (const float*)d_in[2];   // [2304]
    const float* W2 = (const float*)d_in[3];   // [2304][96]
    const float* b2 = (const float*)d_in[4];   // [96]
    float* out = (float*)d_out;

    char* ws = (char*)d_ws;
    unsigned short* xb     = (unsigned short*)(ws);              //  512*768   bf16
    unsigned short* w1t    = (unsigned short*)(ws +   786432);   // 4608*768   bf16
    unsigned short* w2f    = (unsigned short*)(ws +  7864320);   //  72*6*64*8 f16
    unsigned short* headh  = (unsigned short*)(ws +  8306688);   //  512*2304  f16
    unsigned short* tailsw = (unsigned short*)(ws + 10665984);   //  32*36*1024 f16 (2.36MB)
    // total ws use: 13,025,280 bytes

    hipLaunchKernelGGL(k_prep, dim3(3948), dim3(256), 0, stream,
                       x, xb, W1, w1t, W2, w2f);
    hipLaunchKernelGGL(k_gemm1, dim3(36, 8), dim3(256), 0, stream,
                       xb, w1t, b1, headh, tailsw);
    hipLaunchKernelGGL(k_pair, dim3(8, 16, 4), dim3(256), 0, stream,
                       headh, tailsw, w2f, b2, out);
}